// Round 13
// baseline (1825.095 us; speedup 1.0000x reference)
//
#include <hip/hip_runtime.h>
#include <hip/hip_bf16.h>

#define B 4096
#define S 96
#define I_DIM 64
#define HD 128
#define T_STEPS 24
#define N_DIM 64
#define G4 512   // 4*HD
#define BPB 4    // batches per block (two waves each)

typedef unsigned short u16;
typedef __attribute__((ext_vector_type(8))) short bf16x8;
typedef __attribute__((ext_vector_type(4))) float f32x4;

__device__ __forceinline__ u16 f2b(float f) {
    unsigned int u = __float_as_uint(f);
    unsigned int r = (u + 0x7FFFu + ((u >> 16) & 1u)) >> 16;
    return (u16)r;
}
__device__ __forceinline__ float b2f(u16 x) {
    return __uint_as_float(((unsigned int)x) << 16);
}
__device__ __forceinline__ float frcp(float x) { return __builtin_amdgcn_rcpf(x); }
__device__ __forceinline__ float sigm_f(float x) { return frcp(1.0f + __expf(-x)); }
__device__ __forceinline__ float tanh_f(float x) {
    x = fminf(fmaxf(x, -15.f), 15.f);
    float e = __expf(2.0f * x);
    return 1.0f - 2.0f * frcp(e + 1.0f);
}

// ---------------- one-time prep kernels ----------------

__global__ __launch_bounds__(256)
void k_init(const float* __restrict__ h0, const float* __restrict__ c0,
            const float* __restrict__ y0,
            float* __restrict__ h_ws, float* __restrict__ c_ws,
            float* __restrict__ y_ws)
{
    int idx = blockIdx.x * 256 + threadIdx.x;
    if (idx < B * HD) {
        h_ws[idx] = h0[idx];
        c_ws[idx] = c0[idx];
    }
    if (idx < B) y_ws[idx] = y0[idx];
}

// H f32 -> bf16 linear
__global__ __launch_bounds__(256)
void k_prep(const float* __restrict__ H, u16* __restrict__ Hb)
{
    size_t idx = (size_t)blockIdx.x * 256 + threadIdx.x;
    const float4* src = reinterpret_cast<const float4*>(H) + idx * 2;
    float4 v0 = src[0], v1 = src[1];
    ushort4 p0 = { f2b(v0.x), f2b(v0.y), f2b(v0.z), f2b(v0.w) };
    ushort4 p1 = { f2b(v1.x), f2b(v1.y), f2b(v1.z), f2b(v1.w) };
    ushort4* dst = reinterpret_cast<ushort4*>(Hb + idx * 8);
    dst[0] = p0;
    dst[1] = p1;
}

// Score B-frags: group bi = t*8 + nt*2 + ks; elem ((bi*64)+l)*8+j = bf16(Wa[i][t][n])
__global__ __launch_bounds__(64)
void k_prep_S(const float* __restrict__ Wa, u16* __restrict__ BfragS)
{
    int bi = blockIdx.x;            // 192
    int t = bi >> 3, nt = (bi >> 1) & 3, ks = bi & 1;
    int l = threadIdx.x;
    int n = nt * 16 + (l & 15);
    u16 outv[8];
    #pragma unroll
    for (int j = 0; j < 8; ++j) {
        int i = ks * 32 + ((l >> 4) * 8) + j;
        outv[j] = f2b(Wa[(size_t)i * (T_STEPS * N_DIM) + t * N_DIM + n]);
    }
    *reinterpret_cast<int4*>(BfragS + ((size_t)(bi * 64 + l)) * 8) =
        *reinterpret_cast<const int4*>(outv);
}

// Gates B-frags hi/lo
__global__ __launch_bounds__(64)
void k_prep_G(const float* __restrict__ W, const float* __restrict__ U,
              u16* __restrict__ GH, u16* __restrict__ GL)
{
    int bi = blockIdx.x;            // 192
    int ks = bi >> 5, nt = bi & 31;
    int l = threadIdx.x;
    int col = nt * 16 + (l & 15);
    u16 hv[8], lv[8];
    #pragma unroll
    for (int j = 0; j < 8; ++j) {
        int k = ks * 32 + ((l >> 4) * 8) + j;
        float v = (k < 64) ? W[(size_t)k * G4 + col] : U[(size_t)(k - 64) * G4 + col];
        unsigned int ub = __float_as_uint(v);
        u16 hi = (u16)(ub >> 16);
        hv[j] = hi;
        lv[j] = f2b(v - b2f(hi));
    }
    size_t base = ((size_t)(bi * 64 + l)) * 8;
    *reinterpret_cast<int4*>(GH + base) = *reinterpret_cast<const int4*>(hv);
    *reinterpret_cast<int4*>(GL + base) = *reinterpret_cast<const int4*>(lv);
}

// UaT[t][n][hd] = Ua[hd][t][n]
__global__ __launch_bounds__(256)
void k_prep_U(const float* __restrict__ Ua, float* __restrict__ UaT)
{
    int idx = blockIdx.x * 256 + threadIdx.x;    // 196608
    int hd = idx & 127, n = (idx >> 7) & 63, t = idx >> 13;
    UaT[(size_t)t * 8192 + n * 128 + hd] = Ua[(size_t)hd * (T_STEPS * N_DIM) + t * N_DIM + n];
}

// VaT[t][n] = Va[n][t]
__global__ __launch_bounds__(256)
void k_prep_V(const float* __restrict__ Va, float* __restrict__ VaT)
{
    int idx = blockIdx.x * 256 + threadIdx.x;    // 1536
    int n = idx & 63, t = idx >> 6;
    VaT[t * 64 + n] = Va[n * T_STEPS + t];
}

// ---------------- per-step fused kernel (no H LDS tile) ----------------
// 512 threads, 4 batches/block, 2 waves per batch. LDS ~21 KB -> 4 blocks/CU.
template<bool PRE>
__global__ __launch_bounds__(512, 8)
void k_step(const float* __restrict__ H, const u16* __restrict__ Hb,
            const u16* __restrict__ BfragS, const u16* __restrict__ GH,
            const u16* __restrict__ GL, const float* __restrict__ UaT,
            const float* __restrict__ VaT, const float* __restrict__ ba,
            const float* __restrict__ W, const float* __restrict__ bias,
            const float* __restrict__ fc_w, const float* __restrict__ fc_b,
            float* __restrict__ y_ws, float* __restrict__ h_ws,
            float* __restrict__ c_ws, float* __restrict__ out, int t)
{
    __shared__ float cs[BPB][HD];
    __shared__ float hsv[BPB][HD];
    __shared__ float lg[BPB][S];
    __shared__ float xs2[2][BPB][I_DIM];
    __shared__ float part[2][BPB][N_DIM];
    __shared__ float yv[BPB];
    __shared__ float gates[BPB][G4];                  // 8 KB
    __shared__ float ypb[8];
    __shared__ __align__(16) u16 AFh[6][4][32];       // 1.5 KB
    __shared__ __align__(16) u16 AFl[6][4][32];       // 1.5 KB

    const int tid = threadIdx.x;
    const int wv = tid >> 6, l = tid & 63;
    const int q = wv >> 1, half = wv & 1;
    const int b0 = blockIdx.x * BPB, b = b0 + q;
    const int u = half * 64 + l;

    // ---- stage state only ----
    {
        int q2 = tid >> 7, d = tid & 127;
        cs[q2][d]  = c_ws[(size_t)(b0 + q2) * HD + d];
        hsv[q2][d] = h_ws[(size_t)(b0 + q2) * HD + d];
    }
    if (tid < BPB) yv[tid] = y_ws[b0 + tid];
    __syncthreads();

    // ---- score B-frags (precomputed lane layout) ----
    bf16x8 bfr[4][2];
    {
        const bf16x8* bsp = reinterpret_cast<const bf16x8*>(BfragS) + (size_t)t * 8 * 64 + l;
        #pragma unroll
        for (int nt = 0; nt < 4; ++nt)
            #pragma unroll
            for (int ks = 0; ks < 2; ++ks)
                bfr[nt][ks] = bsp[(nt * 2 + ks) * 64];
    }

    // ---- cu partials: lane = n, wave-half sums its 64 hd ----
    {
        const float4* u4 = reinterpret_cast<const float4*>(UaT + (size_t)t * 8192 + l * 128 + half * 64);
        float p = 0.0f;
        #pragma unroll
        for (int k = 0; k < 16; ++k) {
            float4 uv = u4[k];
            float4 cv = *reinterpret_cast<const float4*>(&cs[q][half * 64 + 4 * k]);
            p += uv.x * cv.x + uv.y * cv.y + uv.z * cv.z + uv.w * cv.w;
        }
        part[half][q][l] = p;
    }
    __syncthreads();   // B1

    float cbn = part[0][q][l] + part[1][q][l] + ba[t * 64 + l];
    float van = VaT[t * 64 + l];
    float cbv[4], vav[4];
    #pragma unroll
    for (int nt = 0; nt < 4; ++nt) {
        int n = nt * 16 + (l & 15);
        cbv[nt] = __shfl(cbn, n, 64);
        vav[nt] = __shfl(van, n, 64);
    }

    // ---- score GEMM + tanh + reduce: wave owns 3 of 6 M-tiles ----
    const float scale = 0.08838834764831845f; // 1/sqrt(128)
    const u16* hbase = Hb + (size_t)b * (S * I_DIM);
    const float* hbasef = H + (size_t)b * (S * I_DIM);
    const int kp = (l >> 4) * 8;
    for (int mt = 0; mt < 3; ++mt) {
        int mtile = half * 3 + mt;
        int row = mtile * 16 + (l & 15);
        bf16x8 a0, a1;
        if (PRE) {
            a0 = *reinterpret_cast<const bf16x8*>(hbase + row * I_DIM + kp);
            a1 = *reinterpret_cast<const bf16x8*>(hbase + row * I_DIM + 32 + kp);
        } else {
            const float* hr = hbasef + row * I_DIM;
            u16 t0[8], t1[8];
            #pragma unroll
            for (int j = 0; j < 8; ++j) {
                t0[j] = f2b(hr[kp + j]);
                t1[j] = f2b(hr[32 + kp + j]);
            }
            a0 = *reinterpret_cast<const bf16x8*>(t0);
            a1 = *reinterpret_cast<const bf16x8*>(t1);
        }
        float lgp[4] = {0.f, 0.f, 0.f, 0.f};
        #pragma unroll
        for (int nt = 0; nt < 4; ++nt) {
            f32x4 c = {0.f, 0.f, 0.f, 0.f};
            c = __builtin_amdgcn_mfma_f32_16x16x32_bf16(a0, bfr[nt][0], c, 0, 0, 0);
            c = __builtin_amdgcn_mfma_f32_16x16x32_bf16(a1, bfr[nt][1], c, 0, 0, 0);
            #pragma unroll
            for (int i = 0; i < 4; ++i) {
                float sc = c[i] + cbv[nt];
                sc = fminf(fmaxf(sc, -15.f), 15.f);
                float e = __expf(2.0f * sc);
                float th = 1.0f - 2.0f * frcp(e + 1.0f);
                lgp[i] += th * vav[nt];
            }
        }
        #pragma unroll
        for (int off = 1; off < 16; off <<= 1)
            #pragma unroll
            for (int i = 0; i < 4; ++i) lgp[i] += __shfl_xor(lgp[i], off, 64);
        if ((l & 15) == 0) {
            int g = l >> 4;
            #pragma unroll
            for (int i = 0; i < 4; ++i)
                lg[q][mtile * 16 + g * 4 + i] = lgp[i] * scale;
        }
    }
    __syncthreads();   // B2

    // ---- softmax over S=96 (redundant per wave) ----
    float beta0, beta1;
    {
        float v0 = lg[q][l];
        float v1 = (l < 32) ? lg[q][64 + l] : -1e30f;
        float m = fmaxf(v0, v1);
        #pragma unroll
        for (int off = 32; off; off >>= 1) m = fmaxf(m, __shfl_xor(m, off, 64));
        float e0 = __expf(v0 - m);
        float e1 = (l < 32) ? __expf(v1 - m) : 0.0f;
        float ss = e0 + e1;
        #pragma unroll
        for (int off = 32; off; off >>= 1) ss += __shfl_xor(ss, off, 64);
        float inv = frcp(ss);
        beta0 = e0 * inv;
        beta1 = e1 * inv;
    }
    __syncthreads();   // B3
    if (half == 0) lg[q][l] = beta0;
    else if (l < 32) lg[q][64 + l] = beta1;
    __syncthreads();   // B4

    // ---- ctx partial: wave sums its 48 s-rows from global H (lane = i) ----
    {
        float p = 0.0f;
        #pragma unroll 8
        for (int k = 0; k < 48; ++k) {
            int s = half * 48 + k;
            float hv = PRE ? b2f(hbase[s * I_DIM + l]) : hbasef[s * I_DIM + l];
            p += lg[q][s] * hv;
        }
        xs2[half][q][l] = p;
    }
    __syncthreads();   // B5

    // ---- build gates A-frags (hi/lo split) ----
    #pragma unroll
    for (int it = 0; it < 2; ++it) {
        int idx = tid + 512 * it;
        if (idx < 768) {
            int ks = idx >> 7, rem = idx & 127;
            int r = rem >> 5, kk = rem & 31;
            int k = ks * 32 + kk;
            float f = (k < 64) ? (xs2[0][r][k] + xs2[1][r][k]) : hsv[r][k - 64];
            unsigned int ub = __float_as_uint(f);
            u16 hi = (u16)(ub >> 16);
            AFh[ks][r][kk] = hi;
            AFl[ks][r][kk] = f2b(f - b2f(hi));
        }
    }
    __syncthreads();   // B6

    // ---- gates GEMM via MFMA (3-pass split); wave owns 4 N-tiles ----
    {
        f32x4 acc[4] = {{0.f,0.f,0.f,0.f},{0.f,0.f,0.f,0.f},{0.f,0.f,0.f,0.f},{0.f,0.f,0.f,0.f}};
        const int nt0 = wv * 4;
        const int r = l & 15;
        #pragma unroll
        for (int ks = 0; ks < 6; ++ks) {
            bf16x8 ah = {0,0,0,0,0,0,0,0}, al = {0,0,0,0,0,0,0,0};
            if (r < 4) {
                ah = *reinterpret_cast<const bf16x8*>(&AFh[ks][r][kp]);
                al = *reinterpret_cast<const bf16x8*>(&AFl[ks][r][kp]);
            }
            #pragma unroll
            for (int c2 = 0; c2 < 4; ++c2) {
                size_t base = ((size_t)(ks * 32 + nt0 + c2) * 64 + l);
                bf16x8 bh = reinterpret_cast<const bf16x8*>(GH)[base];
                bf16x8 bl = reinterpret_cast<const bf16x8*>(GL)[base];
                acc[c2] = __builtin_amdgcn_mfma_f32_16x16x32_bf16(ah, bh, acc[c2], 0, 0, 0);
                acc[c2] = __builtin_amdgcn_mfma_f32_16x16x32_bf16(ah, bl, acc[c2], 0, 0, 0);
                acc[c2] = __builtin_amdgcn_mfma_f32_16x16x32_bf16(al, bh, acc[c2], 0, 0, 0);
            }
        }
        if (l < 16) {
            #pragma unroll
            for (int c2 = 0; c2 < 4; ++c2) {
                int j = (nt0 + c2) * 16 + l;
                float bj = bias[j];
                float wy = W[(size_t)I_DIM * G4 + j];
                #pragma unroll
                for (int i = 0; i < 4; ++i)
                    gates[i][j] = acc[c2][i] + bj + yv[i] * wy;
            }
        }
    }
    __syncthreads();   // B7

    // ---- pointwise LSTM + y ----
    {
        int hd = u;
        float ig = gates[q][hd];
        float fg = gates[q][HD + hd];
        float gg = gates[q][2 * HD + hd];
        float og = gates[q][3 * HD + hd];
        float cold = cs[q][hd];
        float cnew = sigm_f(fg) * cold + sigm_f(ig) * tanh_f(gg);
        float hnew = sigm_f(og) * tanh_f(cnew);
        c_ws[(size_t)b * HD + hd] = cnew;
        h_ws[(size_t)b * HD + hd] = hnew;
        out[(size_t)(B * T_STEPS) + ((size_t)b * T_STEPS + t) * HD + hd] = hnew;
        float yp = hnew * fc_w[t * HD + hd];
        #pragma unroll
        for (int off = 32; off; off >>= 1) yp += __shfl_xor(yp, off, 64);
        if (l == 0) ypb[wv] = yp;
    }
    __syncthreads();   // B8
    if (tid < BPB) {
        float y = ypb[2 * tid] + ypb[2 * tid + 1] + fc_b[t];
        y_ws[b0 + tid] = y;
        out[(size_t)(b0 + tid) * T_STEPS + t] = y;
    }
}

extern "C" void kernel_launch(void* const* d_in, const int* in_sizes, int n_in,
                              void* d_out, int out_size, void* d_ws, size_t ws_size,
                              hipStream_t stream)
{
    const float* H    = (const float*)d_in[0];
    const float* y0   = (const float*)d_in[1];
    const float* h0   = (const float*)d_in[2];
    const float* c0   = (const float*)d_in[3];
    const float* Wa   = (const float*)d_in[4];
    const float* Ua   = (const float*)d_in[5];
    const float* ba   = (const float*)d_in[6];
    const float* Va   = (const float*)d_in[7];
    const float* W    = (const float*)d_in[8];
    const float* U    = (const float*)d_in[9];
    const float* bias = (const float*)d_in[10];
    const float* fc_w = (const float*)d_in[11];
    const float* fc_b = (const float*)d_in[12];
    float* out = (float*)d_out;

    u16* BfragS = (u16*)d_ws;                       // 98304 u16
    u16* GH     = BfragS + 98304;                   // 98304
    u16* GL     = GH + 98304;                       // 98304
    float* UaT  = (float*)(GL + 98304);             // 196608 f32
    float* VaT  = UaT + 196608;                     // 1536
    float* h_ws = VaT + 1536;                       // B*HD
    float* c_ws = h_ws + (size_t)B * HD;            // B*HD
    float* y_ws = c_ws + (size_t)B * HD;            // B
    u16*   Hb   = (u16*)(y_ws + B);                 // B*S*I

    size_t need = (size_t)((char*)(Hb + (size_t)B * S * I_DIM) - (char*)d_ws);
    bool pre = ws_size >= need;

    k_init<<<dim3((B * HD + 255) / 256), dim3(256), 0, stream>>>(h0, c0, y0, h_ws, c_ws, y_ws);
    k_prep_S<<<dim3(192), dim3(64), 0, stream>>>(Wa, BfragS);
    k_prep_G<<<dim3(192), dim3(64), 0, stream>>>(W, U, GH, GL);
    k_prep_U<<<dim3(768), dim3(256), 0, stream>>>(Ua, UaT);
    k_prep_V<<<dim3(6), dim3(256), 0, stream>>>(Va, VaT);
    if (pre)
        k_prep<<<dim3(B * S * I_DIM / 8 / 256), dim3(256), 0, stream>>>(H, Hb);

    for (int t = 0; t < T_STEPS; ++t) {
        if (pre)
            k_step<true><<<dim3(B / BPB), dim3(512), 0, stream>>>(H, Hb, BfragS, GH, GL,
                UaT, VaT, ba, W, bias, fc_w, fc_b, y_ws, h_ws, c_ws, out, t);
        else
            k_step<false><<<dim3(B / BPB), dim3(512), 0, stream>>>(H, Hb, BfragS, GH, GL,
                UaT, VaT, ba, W, bias, fc_w, fc_b, y_ws, h_ws, c_ws, out, t);
    }
}

// Round 14
// 1149.141 us; speedup vs baseline: 1.5882x; 1.5882x over previous
//
#include <hip/hip_runtime.h>
#include <hip/hip_bf16.h>

#define B 4096
#define S 96
#define I_DIM 64
#define HD 128
#define T_STEPS 24
#define N_DIM 64
#define G4 512   // 4*HD
#define BPB 4    // batches per block (two waves each)

typedef unsigned short u16;
typedef __attribute__((ext_vector_type(8))) short bf16x8;
typedef __attribute__((ext_vector_type(4))) float f32x4;

__device__ __forceinline__ u16 f2b(float f) {
    unsigned int u = __float_as_uint(f);
    unsigned int r = (u + 0x7FFFu + ((u >> 16) & 1u)) >> 16;
    return (u16)r;
}
__device__ __forceinline__ float b2f(u16 x) {
    return __uint_as_float(((unsigned int)x) << 16);
}
__device__ __forceinline__ float frcp(float x) { return __builtin_amdgcn_rcpf(x); }
__device__ __forceinline__ float sigm_f(float x) { return frcp(1.0f + __expf(-x)); }
__device__ __forceinline__ float tanh_f(float x) {
    x = fminf(fmaxf(x, -15.f), 15.f);
    float e = __expf(2.0f * x);
    return 1.0f - 2.0f * frcp(e + 1.0f);
}

// ---------------- one-time prep kernels ----------------

__global__ __launch_bounds__(256)
void k_init(const float* __restrict__ h0, const float* __restrict__ c0,
            const float* __restrict__ y0,
            float* __restrict__ h_ws, float* __restrict__ c_ws,
            float* __restrict__ y_ws)
{
    int idx = blockIdx.x * 256 + threadIdx.x;
    if (idx < B * HD) {
        h_ws[idx] = h0[idx];
        c_ws[idx] = c0[idx];
    }
    if (idx < B) y_ws[idx] = y0[idx];
}

// H f32 -> bf16 linear
__global__ __launch_bounds__(256)
void k_prep(const float* __restrict__ H, u16* __restrict__ Hb)
{
    size_t idx = (size_t)blockIdx.x * 256 + threadIdx.x;
    const float4* src = reinterpret_cast<const float4*>(H) + idx * 2;
    float4 v0 = src[0], v1 = src[1];
    ushort4 p0 = { f2b(v0.x), f2b(v0.y), f2b(v0.z), f2b(v0.w) };
    ushort4 p1 = { f2b(v1.x), f2b(v1.y), f2b(v1.z), f2b(v1.w) };
    ushort4* dst = reinterpret_cast<ushort4*>(Hb + idx * 8);
    dst[0] = p0;
    dst[1] = p1;
}

// Score B-frags: group bi = t*8 + nt*2 + ks; elem ((bi*64)+l)*8+j = bf16(Wa[i][t][n])
__global__ __launch_bounds__(64)
void k_prep_S(const float* __restrict__ Wa, u16* __restrict__ BfragS)
{
    int bi = blockIdx.x;            // 192
    int t = bi >> 3, nt = (bi >> 1) & 3, ks = bi & 1;
    int l = threadIdx.x;
    int n = nt * 16 + (l & 15);
    u16 outv[8];
    #pragma unroll
    for (int j = 0; j < 8; ++j) {
        int i = ks * 32 + ((l >> 4) * 8) + j;
        outv[j] = f2b(Wa[(size_t)i * (T_STEPS * N_DIM) + t * N_DIM + n]);
    }
    *reinterpret_cast<int4*>(BfragS + ((size_t)(bi * 64 + l)) * 8) =
        *reinterpret_cast<const int4*>(outv);
}

// Gates B-frags hi/lo
__global__ __launch_bounds__(64)
void k_prep_G(const float* __restrict__ W, const float* __restrict__ U,
              u16* __restrict__ GH, u16* __restrict__ GL)
{
    int bi = blockIdx.x;            // 192
    int ks = bi >> 5, nt = bi & 31;
    int l = threadIdx.x;
    int col = nt * 16 + (l & 15);
    u16 hv[8], lv[8];
    #pragma unroll
    for (int j = 0; j < 8; ++j) {
        int k = ks * 32 + ((l >> 4) * 8) + j;
        float v = (k < 64) ? W[(size_t)k * G4 + col] : U[(size_t)(k - 64) * G4 + col];
        unsigned int ub = __float_as_uint(v);
        u16 hi = (u16)(ub >> 16);
        hv[j] = hi;
        lv[j] = f2b(v - b2f(hi));
    }
    size_t base = ((size_t)(bi * 64 + l)) * 8;
    *reinterpret_cast<int4*>(GH + base) = *reinterpret_cast<const int4*>(hv);
    *reinterpret_cast<int4*>(GL + base) = *reinterpret_cast<const int4*>(lv);
}

// UaT[t][n][hd] = Ua[hd][t][n]
__global__ __launch_bounds__(256)
void k_prep_U(const float* __restrict__ Ua, float* __restrict__ UaT)
{
    int idx = blockIdx.x * 256 + threadIdx.x;    // 196608
    int hd = idx & 127, n = (idx >> 7) & 63, t = idx >> 13;
    UaT[(size_t)t * 8192 + n * 128 + hd] = Ua[(size_t)hd * (T_STEPS * N_DIM) + t * N_DIM + n];
}

// VaT[t][n] = Va[n][t]
__global__ __launch_bounds__(256)
void k_prep_V(const float* __restrict__ Va, float* __restrict__ VaT)
{
    int idx = blockIdx.x * 256 + threadIdx.x;    // 1536
    int n = idx & 63, t = idx >> 6;
    VaT[t * 64 + n] = Va[n * T_STEPS + t];
}

// ---------------- per-step fused kernel (no H LDS tile) ----------------
// 512 threads, 4 batches/block, 2 waves per batch. LDS ~21 KB; natural VGPR
// (no min-waves bound -> no forced spill); expect 3-4 blocks/CU.
template<bool PRE>
__global__ __launch_bounds__(512)
void k_step(const float* __restrict__ H, const u16* __restrict__ Hb,
            const u16* __restrict__ BfragS, const u16* __restrict__ GH,
            const u16* __restrict__ GL, const float* __restrict__ UaT,
            const float* __restrict__ VaT, const float* __restrict__ ba,
            const float* __restrict__ W, const float* __restrict__ bias,
            const float* __restrict__ fc_w, const float* __restrict__ fc_b,
            float* __restrict__ y_ws, float* __restrict__ h_ws,
            float* __restrict__ c_ws, float* __restrict__ out, int t)
{
    __shared__ float cs[BPB][HD];
    __shared__ float hsv[BPB][HD];
    __shared__ float lg[BPB][S];
    __shared__ float xs2[2][BPB][I_DIM];
    __shared__ float part[2][BPB][N_DIM];
    __shared__ float yv[BPB];
    __shared__ float gates[BPB][G4];                  // 8 KB
    __shared__ float ypb[8];
    __shared__ __align__(16) u16 AFh[6][4][32];       // 1.5 KB
    __shared__ __align__(16) u16 AFl[6][4][32];       // 1.5 KB

    const int tid = threadIdx.x;
    const int wv = tid >> 6, l = tid & 63;
    const int q = wv >> 1, half = wv & 1;
    const int b0 = blockIdx.x * BPB, b = b0 + q;
    const int u = half * 64 + l;

    // ---- stage state only ----
    {
        int q2 = tid >> 7, d = tid & 127;
        cs[q2][d]  = c_ws[(size_t)(b0 + q2) * HD + d];
        hsv[q2][d] = h_ws[(size_t)(b0 + q2) * HD + d];
    }
    if (tid < BPB) yv[tid] = y_ws[b0 + tid];
    __syncthreads();

    // ---- score B-frags (precomputed lane layout) ----
    bf16x8 bfr[4][2];
    {
        const bf16x8* bsp = reinterpret_cast<const bf16x8*>(BfragS) + (size_t)t * 8 * 64 + l;
        #pragma unroll
        for (int nt = 0; nt < 4; ++nt)
            #pragma unroll
            for (int ks = 0; ks < 2; ++ks)
                bfr[nt][ks] = bsp[(nt * 2 + ks) * 64];
    }

    // ---- cu partials: lane = n, wave-half sums its 64 hd ----
    {
        const float4* u4 = reinterpret_cast<const float4*>(UaT + (size_t)t * 8192 + l * 128 + half * 64);
        float p = 0.0f;
        #pragma unroll
        for (int k = 0; k < 16; ++k) {
            float4 uv = u4[k];
            float4 cv = *reinterpret_cast<const float4*>(&cs[q][half * 64 + 4 * k]);
            p += uv.x * cv.x + uv.y * cv.y + uv.z * cv.z + uv.w * cv.w;
        }
        part[half][q][l] = p;
    }
    __syncthreads();   // B1

    float cbn = part[0][q][l] + part[1][q][l] + ba[t * 64 + l];
    float van = VaT[t * 64 + l];
    float cbv[4], vav[4];
    #pragma unroll
    for (int nt = 0; nt < 4; ++nt) {
        int n = nt * 16 + (l & 15);
        cbv[nt] = __shfl(cbn, n, 64);
        vav[nt] = __shfl(van, n, 64);
    }

    // ---- score GEMM + tanh + reduce: wave owns 3 of 6 M-tiles ----
    const float scale = 0.08838834764831845f; // 1/sqrt(128)
    const u16* hbase = Hb + (size_t)b * (S * I_DIM);
    const float* hbasef = H + (size_t)b * (S * I_DIM);
    const int kp = (l >> 4) * 8;
    for (int mt = 0; mt < 3; ++mt) {
        int mtile = half * 3 + mt;
        int row = mtile * 16 + (l & 15);
        bf16x8 a0, a1;
        if (PRE) {
            a0 = *reinterpret_cast<const bf16x8*>(hbase + row * I_DIM + kp);
            a1 = *reinterpret_cast<const bf16x8*>(hbase + row * I_DIM + 32 + kp);
        } else {
            const float* hr = hbasef + row * I_DIM;
            u16 t0[8], t1[8];
            #pragma unroll
            for (int j = 0; j < 8; ++j) {
                t0[j] = f2b(hr[kp + j]);
                t1[j] = f2b(hr[32 + kp + j]);
            }
            a0 = *reinterpret_cast<const bf16x8*>(t0);
            a1 = *reinterpret_cast<const bf16x8*>(t1);
        }
        float lgp[4] = {0.f, 0.f, 0.f, 0.f};
        #pragma unroll
        for (int nt = 0; nt < 4; ++nt) {
            f32x4 c = {0.f, 0.f, 0.f, 0.f};
            c = __builtin_amdgcn_mfma_f32_16x16x32_bf16(a0, bfr[nt][0], c, 0, 0, 0);
            c = __builtin_amdgcn_mfma_f32_16x16x32_bf16(a1, bfr[nt][1], c, 0, 0, 0);
            #pragma unroll
            for (int i = 0; i < 4; ++i) {
                float sc = c[i] + cbv[nt];
                sc = fminf(fmaxf(sc, -15.f), 15.f);
                float e = __expf(2.0f * sc);
                float th = 1.0f - 2.0f * frcp(e + 1.0f);
                lgp[i] += th * vav[nt];
            }
        }
        #pragma unroll
        for (int off = 1; off < 16; off <<= 1)
            #pragma unroll
            for (int i = 0; i < 4; ++i) lgp[i] += __shfl_xor(lgp[i], off, 64);
        if ((l & 15) == 0) {
            int g = l >> 4;
            #pragma unroll
            for (int i = 0; i < 4; ++i)
                lg[q][mtile * 16 + g * 4 + i] = lgp[i] * scale;
        }
    }
    __syncthreads();   // B2

    // ---- softmax over S=96 (redundant per wave) ----
    float beta0, beta1;
    {
        float v0 = lg[q][l];
        float v1 = (l < 32) ? lg[q][64 + l] : -1e30f;
        float m = fmaxf(v0, v1);
        #pragma unroll
        for (int off = 32; off; off >>= 1) m = fmaxf(m, __shfl_xor(m, off, 64));
        float e0 = __expf(v0 - m);
        float e1 = (l < 32) ? __expf(v1 - m) : 0.0f;
        float ss = e0 + e1;
        #pragma unroll
        for (int off = 32; off; off >>= 1) ss += __shfl_xor(ss, off, 64);
        float inv = frcp(ss);
        beta0 = e0 * inv;
        beta1 = e1 * inv;
    }
    __syncthreads();   // B3
    if (half == 0) lg[q][l] = beta0;
    else if (l < 32) lg[q][64 + l] = beta1;
    __syncthreads();   // B4

    // ---- ctx partial: wave sums its 48 s-rows from global H (lane = i) ----
    {
        float p = 0.0f;
        #pragma unroll 8
        for (int k = 0; k < 48; ++k) {
            int s = half * 48 + k;
            float hv = PRE ? b2f(hbase[s * I_DIM + l]) : hbasef[s * I_DIM + l];
            p += lg[q][s] * hv;
        }
        xs2[half][q][l] = p;
    }
    __syncthreads();   // B5

    // ---- build gates A-frags (hi/lo split) ----
    #pragma unroll
    for (int it = 0; it < 2; ++it) {
        int idx = tid + 512 * it;
        if (idx < 768) {
            int ks = idx >> 7, rem = idx & 127;
            int r = rem >> 5, kk = rem & 31;
            int k = ks * 32 + kk;
            float f = (k < 64) ? (xs2[0][r][k] + xs2[1][r][k]) : hsv[r][k - 64];
            unsigned int ub = __float_as_uint(f);
            u16 hi = (u16)(ub >> 16);
            AFh[ks][r][kk] = hi;
            AFl[ks][r][kk] = f2b(f - b2f(hi));
        }
    }
    __syncthreads();   // B6

    // ---- gates GEMM via MFMA (3-pass split); wave owns 4 N-tiles ----
    {
        f32x4 acc[4] = {{0.f,0.f,0.f,0.f},{0.f,0.f,0.f,0.f},{0.f,0.f,0.f,0.f},{0.f,0.f,0.f,0.f}};
        const int nt0 = wv * 4;
        const int r = l & 15;
        #pragma unroll
        for (int ks = 0; ks < 6; ++ks) {
            bf16x8 ah = {0,0,0,0,0,0,0,0}, al = {0,0,0,0,0,0,0,0};
            if (r < 4) {
                ah = *reinterpret_cast<const bf16x8*>(&AFh[ks][r][kp]);
                al = *reinterpret_cast<const bf16x8*>(&AFl[ks][r][kp]);
            }
            #pragma unroll
            for (int c2 = 0; c2 < 4; ++c2) {
                size_t base = ((size_t)(ks * 32 + nt0 + c2) * 64 + l);
                bf16x8 bh = reinterpret_cast<const bf16x8*>(GH)[base];
                bf16x8 bl = reinterpret_cast<const bf16x8*>(GL)[base];
                acc[c2] = __builtin_amdgcn_mfma_f32_16x16x32_bf16(ah, bh, acc[c2], 0, 0, 0);
                acc[c2] = __builtin_amdgcn_mfma_f32_16x16x32_bf16(ah, bl, acc[c2], 0, 0, 0);
                acc[c2] = __builtin_amdgcn_mfma_f32_16x16x32_bf16(al, bh, acc[c2], 0, 0, 0);
            }
        }
        if (l < 16) {
            #pragma unroll
            for (int c2 = 0; c2 < 4; ++c2) {
                int j = (nt0 + c2) * 16 + l;
                float bj = bias[j];
                float wy = W[(size_t)I_DIM * G4 + j];
                #pragma unroll
                for (int i = 0; i < 4; ++i)
                    gates[i][j] = acc[c2][i] + bj + yv[i] * wy;
            }
        }
    }
    __syncthreads();   // B7

    // ---- pointwise LSTM + y ----
    {
        int hd = u;
        float ig = gates[q][hd];
        float fg = gates[q][HD + hd];
        float gg = gates[q][2 * HD + hd];
        float og = gates[q][3 * HD + hd];
        float cold = cs[q][hd];
        float cnew = sigm_f(fg) * cold + sigm_f(ig) * tanh_f(gg);
        float hnew = sigm_f(og) * tanh_f(cnew);
        c_ws[(size_t)b * HD + hd] = cnew;
        h_ws[(size_t)b * HD + hd] = hnew;
        out[(size_t)(B * T_STEPS) + ((size_t)b * T_STEPS + t) * HD + hd] = hnew;
        float yp = hnew * fc_w[t * HD + hd];
        #pragma unroll
        for (int off = 32; off; off >>= 1) yp += __shfl_xor(yp, off, 64);
        if (l == 0) ypb[wv] = yp;
    }
    __syncthreads();   // B8
    if (tid < BPB) {
        float y = ypb[2 * tid] + ypb[2 * tid + 1] + fc_b[t];
        y_ws[b0 + tid] = y;
        out[(size_t)(b0 + tid) * T_STEPS + t] = y;
    }
}

extern "C" void kernel_launch(void* const* d_in, const int* in_sizes, int n_in,
                              void* d_out, int out_size, void* d_ws, size_t ws_size,
                              hipStream_t stream)
{
    const float* H    = (const float*)d_in[0];
    const float* y0   = (const float*)d_in[1];
    const float* h0   = (const float*)d_in[2];
    const float* c0   = (const float*)d_in[3];
    const float* Wa   = (const float*)d_in[4];
    const float* Ua   = (const float*)d_in[5];
    const float* ba   = (const float*)d_in[6];
    const float* Va   = (const float*)d_in[7];
    const float* W    = (const float*)d_in[8];
    const float* U    = (const float*)d_in[9];
    const float* bias = (const float*)d_in[10];
    const float* fc_w = (const float*)d_in[11];
    const float* fc_b = (const float*)d_in[12];
    float* out = (float*)d_out;

    u16* BfragS = (u16*)d_ws;                       // 98304 u16
    u16* GH     = BfragS + 98304;                   // 98304
    u16* GL     = GH + 98304;                       // 98304
    float* UaT  = (float*)(GL + 98304);             // 196608 f32
    float* VaT  = UaT + 196608;                     // 1536
    float* h_ws = VaT + 1536;                       // B*HD
    float* c_ws = h_ws + (size_t)B * HD;            // B*HD
    float* y_ws = c_ws + (size_t)B * HD;            // B
    u16*   Hb   = (u16*)(y_ws + B);                 // B*S*I

    size_t need = (size_t)((char*)(Hb + (size_t)B * S * I_DIM) - (char*)d_ws);
    bool pre = ws_size >= need;

    k_init<<<dim3((B * HD + 255) / 256), dim3(256), 0, stream>>>(h0, c0, y0, h_ws, c_ws, y_ws);
    k_prep_S<<<dim3(192), dim3(64), 0, stream>>>(Wa, BfragS);
    k_prep_G<<<dim3(192), dim3(64), 0, stream>>>(W, U, GH, GL);
    k_prep_U<<<dim3(768), dim3(256), 0, stream>>>(Ua, UaT);
    k_prep_V<<<dim3(6), dim3(256), 0, stream>>>(Va, VaT);
    if (pre)
        k_prep<<<dim3(B * S * I_DIM / 8 / 256), dim3(256), 0, stream>>>(H, Hb);

    for (int t = 0; t < T_STEPS; ++t) {
        if (pre)
            k_step<true><<<dim3(B / BPB), dim3(512), 0, stream>>>(H, Hb, BfragS, GH, GL,
                UaT, VaT, ba, W, bias, fc_w, fc_b, y_ws, h_ws, c_ws, out, t);
        else
            k_step<false><<<dim3(B / BPB), dim3(512), 0, stream>>>(H, Hb, BfragS, GH, GL,
                UaT, VaT, ba, W, bias, fc_w, fc_b, y_ws, h_ws, c_ws, out, t);
    }
}

// Round 16
// 991.448 us; speedup vs baseline: 1.8408x; 1.1591x over previous
//
#include <hip/hip_runtime.h>
#include <hip/hip_bf16.h>

#define B 4096
#define S 96
#define I_DIM 64
#define HD 128
#define T_STEPS 24
#define N_DIM 64
#define G4 512   // 4*HD
#define BPB 8    // batches per block: one wave each (8 waves, 512 threads)

typedef unsigned short u16;
typedef __attribute__((ext_vector_type(8))) short bf16x8;
typedef __attribute__((ext_vector_type(4))) float f32x4;

__device__ __forceinline__ u16 f2b(float f) {
    unsigned int u = __float_as_uint(f);
    unsigned int r = (u + 0x7FFFu + ((u >> 16) & 1u)) >> 16;
    return (u16)r;
}
__device__ __forceinline__ float b2f(u16 x) {
    return __uint_as_float(((unsigned int)x) << 16);
}
__device__ __forceinline__ float frcp(float x) { return __builtin_amdgcn_rcpf(x); }
__device__ __forceinline__ float sigm_f(float x) { return frcp(1.0f + __expf(-x)); }
__device__ __forceinline__ float tanh_f(float x) {
    x = fminf(fmaxf(x, -15.f), 15.f);
    float e = __expf(2.0f * x);
    return 1.0f - 2.0f * frcp(e + 1.0f);
}

// ---------------- one-time prep kernels ----------------

__global__ __launch_bounds__(256)
void k_init(const float* __restrict__ h0, const float* __restrict__ c0,
            const float* __restrict__ y0,
            float* __restrict__ h_ws, float* __restrict__ c_ws,
            float* __restrict__ y_ws)
{
    int idx = blockIdx.x * 256 + threadIdx.x;
    if (idx < B * HD) {
        h_ws[idx] = h0[idx];
        c_ws[idx] = c0[idx];
    }
    if (idx < B) y_ws[idx] = y0[idx];
}

// H f32 -> bf16 linear
__global__ __launch_bounds__(256)
void k_prep(const float* __restrict__ H, u16* __restrict__ Hb)
{
    size_t idx = (size_t)blockIdx.x * 256 + threadIdx.x;
    const float4* src = reinterpret_cast<const float4*>(H) + idx * 2;
    float4 v0 = src[0], v1 = src[1];
    ushort4 p0 = { f2b(v0.x), f2b(v0.y), f2b(v0.z), f2b(v0.w) };
    ushort4 p1 = { f2b(v1.x), f2b(v1.y), f2b(v1.z), f2b(v1.w) };
    ushort4* dst = reinterpret_cast<ushort4*>(Hb + idx * 8);
    dst[0] = p0;
    dst[1] = p1;
}

// Score B-frags: group bi = t*8 + nt*2 + ks; elem ((bi*64)+l)*8+j = bf16(Wa[i][t][n])
__global__ __launch_bounds__(64)
void k_prep_S(const float* __restrict__ Wa, u16* __restrict__ BfragS)
{
    int bi = blockIdx.x;            // 192
    int t = bi >> 3, nt = (bi >> 1) & 3, ks = bi & 1;
    int l = threadIdx.x;
    int n = nt * 16 + (l & 15);
    u16 outv[8];
    #pragma unroll
    for (int j = 0; j < 8; ++j) {
        int i = ks * 32 + ((l >> 4) * 8) + j;
        outv[j] = f2b(Wa[(size_t)i * (T_STEPS * N_DIM) + t * N_DIM + n]);
    }
    *reinterpret_cast<int4*>(BfragS + ((size_t)(bi * 64 + l)) * 8) =
        *reinterpret_cast<const int4*>(outv);
}

// Gates B-frags hi/lo
__global__ __launch_bounds__(64)
void k_prep_G(const float* __restrict__ W, const float* __restrict__ U,
              u16* __restrict__ GH, u16* __restrict__ GL)
{
    int bi = blockIdx.x;            // 192
    int ks = bi >> 5, nt = bi & 31;
    int l = threadIdx.x;
    int col = nt * 16 + (l & 15);
    u16 hv[8], lv[8];
    #pragma unroll
    for (int j = 0; j < 8; ++j) {
        int k = ks * 32 + ((l >> 4) * 8) + j;
        float v = (k < 64) ? W[(size_t)k * G4 + col] : U[(size_t)(k - 64) * G4 + col];
        unsigned int ub = __float_as_uint(v);
        u16 hi = (u16)(ub >> 16);
        hv[j] = hi;
        lv[j] = f2b(v - b2f(hi));
    }
    size_t base = ((size_t)(bi * 64 + l)) * 8;
    *reinterpret_cast<int4*>(GH + base) = *reinterpret_cast<const int4*>(hv);
    *reinterpret_cast<int4*>(GL + base) = *reinterpret_cast<const int4*>(lv);
}

// UaT[t][n][hd] = Ua[hd][t][n]
__global__ __launch_bounds__(256)
void k_prep_U(const float* __restrict__ Ua, float* __restrict__ UaT)
{
    int idx = blockIdx.x * 256 + threadIdx.x;    // 196608
    int hd = idx & 127, n = (idx >> 7) & 63, t = idx >> 13;
    UaT[(size_t)t * 8192 + n * 128 + hd] = Ua[(size_t)hd * (T_STEPS * N_DIM) + t * N_DIM + n];
}

// VaT[t][n] = Va[n][t]
__global__ __launch_bounds__(256)
void k_prep_V(const float* __restrict__ Va, float* __restrict__ VaT)
{
    int idx = blockIdx.x * 256 + threadIdx.x;    // 1536
    int n = idx & 63, t = idx >> 6;
    VaT[t * 64 + n] = Va[n * T_STEPS + t];
}

// ---------------- per-step fused kernel: wave-per-batch ----------------
// 512 threads = 8 waves; wave w owns batch b0+w for all of attention; gates
// GEMM packs M=8 batches. LDS ~35 KB; 4 barriers per step.
template<bool PRE>
__global__ __launch_bounds__(512)
void k_step(const float* __restrict__ H, const u16* __restrict__ Hb,
            const u16* __restrict__ BfragS, const u16* __restrict__ GH,
            const u16* __restrict__ GL, const float* __restrict__ UaT,
            const float* __restrict__ VaT, const float* __restrict__ ba,
            const float* __restrict__ W, const float* __restrict__ bias,
            const float* __restrict__ fc_w, const float* __restrict__ fc_b,
            float* __restrict__ y_ws, float* __restrict__ h_ws,
            float* __restrict__ c_ws, float* __restrict__ out, int t)
{
    __shared__ float cs[BPB][HD];                     // 4 KB
    __shared__ float hsv[BPB][HD];                    // 4 KB
    __shared__ float lg[BPB][S];                      // 3 KB
    __shared__ float xs[BPB][I_DIM];                  // 2 KB
    __shared__ float yv[BPB];
    __shared__ float gates[BPB][G4];                  // 16 KB
    __shared__ __align__(16) u16 AFh[6][BPB][32];     // 3 KB
    __shared__ __align__(16) u16 AFl[6][BPB][32];     // 3 KB

    const int tid = threadIdx.x;
    const int w = tid >> 6, l = tid & 63;             // wave = local batch
    const int b0 = blockIdx.x * BPB, b = b0 + w;

    // ---- stage state (wave w loads batch w's state) ----
    {
        int q2 = tid >> 6, d = l;
        cs[q2][d]        = c_ws[(size_t)(b0 + q2) * HD + d];
        cs[q2][d + 64]   = c_ws[(size_t)(b0 + q2) * HD + d + 64];
        hsv[q2][d]       = h_ws[(size_t)(b0 + q2) * HD + d];
        hsv[q2][d + 64]  = h_ws[(size_t)(b0 + q2) * HD + d + 64];
    }
    if (tid < BPB) yv[tid] = y_ws[b0 + tid];
    __syncthreads();   // B_a

    // ---- score B-frags (precomputed lane layout; shared across batches) ----
    bf16x8 bfr[4][2];
    {
        const bf16x8* bsp = reinterpret_cast<const bf16x8*>(BfragS) + (size_t)t * 8 * 64 + l;
        #pragma unroll
        for (int nt = 0; nt < 4; ++nt)
            #pragma unroll
            for (int ks = 0; ks < 2; ++ks)
                bfr[nt][ks] = bsp[(nt * 2 + ks) * 64];
    }

    // ---- cu[n]: lane n sums all 128 hd (wave-local, no barrier) ----
    float cbn;
    {
        const float4* u4 = reinterpret_cast<const float4*>(UaT + (size_t)t * 8192 + l * 128);
        float p = 0.0f;
        #pragma unroll
        for (int k = 0; k < 32; ++k) {
            float4 uv = u4[k];
            float4 cv = *reinterpret_cast<const float4*>(&cs[w][4 * k]);
            p += uv.x * cv.x + uv.y * cv.y + uv.z * cv.z + uv.w * cv.w;
        }
        cbn = p + ba[t * 64 + l];
    }
    float van = VaT[t * 64 + l];
    float cbv[4], vav[4];
    #pragma unroll
    for (int nt = 0; nt < 4; ++nt) {
        int n = nt * 16 + (l & 15);
        cbv[nt] = __shfl(cbn, n, 64);
        vav[nt] = __shfl(van, n, 64);
    }

    // ---- score GEMM + tanh + reduce: wave does all 6 M-tiles of its batch ----
    const float scale = 0.08838834764831845f; // 1/sqrt(128)
    const u16* hbase = Hb + (size_t)b * (S * I_DIM);
    const float* hbasef = H + (size_t)b * (S * I_DIM);
    const int kp = (l >> 4) * 8;
    for (int mt = 0; mt < 6; ++mt) {
        int row = mt * 16 + (l & 15);
        bf16x8 a0, a1;
        if (PRE) {
            a0 = *reinterpret_cast<const bf16x8*>(hbase + row * I_DIM + kp);
            a1 = *reinterpret_cast<const bf16x8*>(hbase + row * I_DIM + 32 + kp);
        } else {
            const float* hr = hbasef + row * I_DIM;
            u16 t0[8], t1[8];
            #pragma unroll
            for (int j = 0; j < 8; ++j) {
                t0[j] = f2b(hr[kp + j]);
                t1[j] = f2b(hr[32 + kp + j]);
            }
            a0 = *reinterpret_cast<const bf16x8*>(t0);
            a1 = *reinterpret_cast<const bf16x8*>(t1);
        }
        float lgp[4] = {0.f, 0.f, 0.f, 0.f};
        #pragma unroll
        for (int nt = 0; nt < 4; ++nt) {
            f32x4 c = {0.f, 0.f, 0.f, 0.f};
            c = __builtin_amdgcn_mfma_f32_16x16x32_bf16(a0, bfr[nt][0], c, 0, 0, 0);
            c = __builtin_amdgcn_mfma_f32_16x16x32_bf16(a1, bfr[nt][1], c, 0, 0, 0);
            #pragma unroll
            for (int i = 0; i < 4; ++i) {
                float sc = c[i] + cbv[nt];
                sc = fminf(fmaxf(sc, -15.f), 15.f);
                float e = __expf(2.0f * sc);
                float th = 1.0f - 2.0f * frcp(e + 1.0f);
                lgp[i] += th * vav[nt];
            }
        }
        #pragma unroll
        for (int off = 1; off < 16; off <<= 1)
            #pragma unroll
            for (int i = 0; i < 4; ++i) lgp[i] += __shfl_xor(lgp[i], off, 64);
        if ((l & 15) == 0) {
            int g = l >> 4;
            #pragma unroll
            for (int i = 0; i < 4; ++i)
                lg[w][mt * 16 + g * 4 + i] = lgp[i] * scale;
        }
    }

    // ---- softmax over S=96 (wave-local; same wave wrote lg[w]) ----
    {
        float v0 = lg[w][l];
        float v1 = (l < 32) ? lg[w][64 + l] : -1e30f;
        float m = fmaxf(v0, v1);
        #pragma unroll
        for (int off = 32; off; off >>= 1) m = fmaxf(m, __shfl_xor(m, off, 64));
        float e0 = __expf(v0 - m);
        float e1 = (l < 32) ? __expf(v1 - m) : 0.0f;
        float ss = e0 + e1;
        #pragma unroll
        for (int off = 32; off; off >>= 1) ss += __shfl_xor(ss, off, 64);
        float inv = frcp(ss);
        lg[w][l] = e0 * inv;
        if (l < 32) lg[w][64 + l] = e1 * inv;
    }

    // ---- ctx: lane i = l sums 96 s-rows (wave-local) ----
    {
        float p = 0.0f;
        #pragma unroll 8
        for (int s = 0; s < S; ++s) {
            float hv = PRE ? b2f(hbase[s * I_DIM + l]) : hbasef[s * I_DIM + l];
            p += lg[w][s] * hv;
        }
        xs[w][l] = p;
    }
    __syncthreads();   // B_b (xs of all batches ready)

    // ---- build gates A-frags (hi/lo split), 8 batches x 192 K ----
    #pragma unroll
    for (int it = 0; it < 3; ++it) {
        int idx = tid + 512 * it;   // 0..1535
        int ks = idx >> 8, rem = idx & 255;
        int r = rem >> 5, kk = rem & 31;
        int k = ks * 32 + kk;
        float f = (k < 64) ? xs[r][k] : hsv[r][k - 64];
        unsigned int ub = __float_as_uint(f);
        u16 hi = (u16)(ub >> 16);
        AFh[ks][r][kk] = hi;
        AFl[ks][r][kk] = f2b(f - b2f(hi));
    }
    __syncthreads();   // B_c

    // ---- gates GEMM via MFMA (3-pass split, M=8); wave owns 4 N-tiles ----
    {
        f32x4 acc[4] = {{0.f,0.f,0.f,0.f},{0.f,0.f,0.f,0.f},{0.f,0.f,0.f,0.f},{0.f,0.f,0.f,0.f}};
        const int nt0 = w * 4;
        const int r = l & 15;
        #pragma unroll
        for (int ks = 0; ks < 6; ++ks) {
            bf16x8 ah = {0,0,0,0,0,0,0,0}, al = {0,0,0,0,0,0,0,0};
            if (r < 8) {
                ah = *reinterpret_cast<const bf16x8*>(&AFh[ks][r][kp]);
                al = *reinterpret_cast<const bf16x8*>(&AFl[ks][r][kp]);
            }
            #pragma unroll
            for (int c2 = 0; c2 < 4; ++c2) {
                size_t base = ((size_t)(ks * 32 + nt0 + c2) * 64 + l);
                bf16x8 bh = reinterpret_cast<const bf16x8*>(GH)[base];
                bf16x8 bl = reinterpret_cast<const bf16x8*>(GL)[base];
                acc[c2] = __builtin_amdgcn_mfma_f32_16x16x32_bf16(ah, bh, acc[c2], 0, 0, 0);
                acc[c2] = __builtin_amdgcn_mfma_f32_16x16x32_bf16(ah, bl, acc[c2], 0, 0, 0);
                acc[c2] = __builtin_amdgcn_mfma_f32_16x16x32_bf16(al, bh, acc[c2], 0, 0, 0);
            }
        }
        // C/D: col = lane&15, row = (lane>>4)*4 + i; rows 0-7 = batches 0-7
        if (l < 32) {
            #pragma unroll
            for (int c2 = 0; c2 < 4; ++c2) {
                int j = (nt0 + c2) * 16 + (l & 15);
                float bj = bias[j];
                float wy = W[(size_t)I_DIM * G4 + j];
                int i0 = (l >> 4) * 4;
                #pragma unroll
                for (int i = 0; i < 4; ++i)
                    gates[i0 + i][j] = acc[c2][i] + bj + yv[i0 + i] * wy;
            }
        }
    }
    __syncthreads();   // B_d

    // ---- pointwise LSTM + y: wave w owns batch b (hd = l, l+64) ----
    {
        float yp = 0.0f;
        #pragma unroll
        for (int m = 0; m < 2; ++m) {
            int hd = l + 64 * m;
            float ig = gates[w][hd];
            float fg = gates[w][HD + hd];
            float gg = gates[w][2 * HD + hd];
            float og = gates[w][3 * HD + hd];
            float cold = cs[w][hd];
            float cnew = sigm_f(fg) * cold + sigm_f(ig) * tanh_f(gg);
            float hnew = sigm_f(og) * tanh_f(cnew);
            c_ws[(size_t)b * HD + hd] = cnew;
            h_ws[(size_t)b * HD + hd] = hnew;
            out[(size_t)(B * T_STEPS) + ((size_t)b * T_STEPS + t) * HD + hd] = hnew;
            yp += hnew * fc_w[t * HD + hd];
        }
        #pragma unroll
        for (int off = 32; off; off >>= 1) yp += __shfl_xor(yp, off, 64);
        if (l == 0) {
            float y = yp + fc_b[t];
            y_ws[b] = y;
            out[(size_t)b * T_STEPS + t] = y;
        }
    }
}

extern "C" void kernel_launch(void* const* d_in, const int* in_sizes, int n_in,
                              void* d_out, int out_size, void* d_ws, size_t ws_size,
                              hipStream_t stream)
{
    const float* H    = (const float*)d_in[0];
    const float* y0   = (const float*)d_in[1];
    const float* h0   = (const float*)d_in[2];
    const float* c0   = (const float*)d_in[3];
    const float* Wa   = (const float*)d_in[4];
    const float* Ua   = (const float*)d_in[5];
    const float* ba   = (const float*)d_in[6];
    const float* Va   = (const float*)d_in[7];
    const float* W    = (const float*)d_in[8];
    const float* U    = (const float*)d_in[9];
    const float* bias = (const float*)d_in[10];
    const float* fc_w = (const float*)d_in[11];
    const float* fc_b = (const float*)d_in[12];
    float* out = (float*)d_out;

    u16* BfragS = (u16*)d_ws;                       // 98304 u16
    u16* GH     = BfragS + 98304;                   // 98304
    u16* GL     = GH + 98304;                       // 98304
    float* UaT  = (float*)(GL + 98304);             // 196608 f32
    float* VaT  = UaT + 196608;                     // 1536
    float* h_ws = VaT + 1536;                       // B*HD
    float* c_ws = h_ws + (size_t)B * HD;            // B*HD
    float* y_ws = c_ws + (size_t)B * HD;            // B
    u16*   Hb   = (u16*)(y_ws + B);                 // B*S*I

    size_t need = (size_t)((char*)(Hb + (size_t)B * S * I_DIM) - (char*)d_ws);
    bool pre = ws_size >= need;

    k_init<<<dim3((B * HD + 255) / 256), dim3(256), 0, stream>>>(h0, c0, y0, h_ws, c_ws, y_ws);
    k_prep_S<<<dim3(192), dim3(64), 0, stream>>>(Wa, BfragS);
    k_prep_G<<<dim3(192), dim3(64), 0, stream>>>(W, U, GH, GL);
    k_prep_U<<<dim3(768), dim3(256), 0, stream>>>(Ua, UaT);
    k_prep_V<<<dim3(6), dim3(256), 0, stream>>>(Va, VaT);
    if (pre)
        k_prep<<<dim3(B * S * I_DIM / 8 / 256), dim3(256), 0, stream>>>(H, Hb);

    for (int t = 0; t < T_STEPS; ++t) {
        if (pre)
            k_step<true><<<dim3(B / BPB), dim3(512), 0, stream>>>(H, Hb, BfragS, GH, GL,
                UaT, VaT, ba, W, bias, fc_w, fc_b, y_ws, h_ws, c_ws, out, t);
        else
            k_step<false><<<dim3(B / BPB), dim3(512), 0, stream>>>(H, Hb, BfragS, GH, GL,
                UaT, VaT, ba, W, bias, fc_w, fc_b, y_ws, h_ws, c_ws, out, t);
    }
}

// Round 17
// 881.103 us; speedup vs baseline: 2.0714x; 1.1252x over previous
//
#include <hip/hip_runtime.h>
#include <hip/hip_bf16.h>

#define B 4096
#define S 96
#define I_DIM 64
#define HD 128
#define T_STEPS 24
#define N_DIM 64
#define G4 512   // 4*HD
#define BPB 16   // batches per block: one wave each (16 waves, 1024 threads)

typedef unsigned short u16;
typedef __attribute__((ext_vector_type(8))) short bf16x8;
typedef __attribute__((ext_vector_type(4))) float f32x4;

__device__ __forceinline__ u16 f2b(float f) {
    unsigned int u = __float_as_uint(f);
    unsigned int r = (u + 0x7FFFu + ((u >> 16) & 1u)) >> 16;
    return (u16)r;
}
__device__ __forceinline__ float b2f(u16 x) {
    return __uint_as_float(((unsigned int)x) << 16);
}
__device__ __forceinline__ float frcp(float x) { return __builtin_amdgcn_rcpf(x); }
__device__ __forceinline__ float sigm_f(float x) { return frcp(1.0f + __expf(-x)); }
__device__ __forceinline__ float tanh_f(float x) {
    x = fminf(fmaxf(x, -15.f), 15.f);
    float e = __expf(2.0f * x);
    return 1.0f - 2.0f * frcp(e + 1.0f);
}

// ---------------- one-time prep kernels ----------------

__global__ __launch_bounds__(256)
void k_init(const float* __restrict__ h0, const float* __restrict__ c0,
            const float* __restrict__ y0,
            float* __restrict__ h_ws, float* __restrict__ c_ws,
            float* __restrict__ y_ws)
{
    int idx = blockIdx.x * 256 + threadIdx.x;
    if (idx < B * HD) {
        h_ws[idx] = h0[idx];
        c_ws[idx] = c0[idx];
    }
    if (idx < B) y_ws[idx] = y0[idx];
}

// H f32 -> bf16 linear
__global__ __launch_bounds__(256)
void k_prep(const float* __restrict__ H, u16* __restrict__ Hb)
{
    size_t idx = (size_t)blockIdx.x * 256 + threadIdx.x;
    const float4* src = reinterpret_cast<const float4*>(H) + idx * 2;
    float4 v0 = src[0], v1 = src[1];
    ushort4 p0 = { f2b(v0.x), f2b(v0.y), f2b(v0.z), f2b(v0.w) };
    ushort4 p1 = { f2b(v1.x), f2b(v1.y), f2b(v1.z), f2b(v1.w) };
    ushort4* dst = reinterpret_cast<ushort4*>(Hb + idx * 8);
    dst[0] = p0;
    dst[1] = p1;
}

// Score B-frags: group bi = t*8 + nt*2 + ks; elem ((bi*64)+l)*8+j = bf16(Wa[i][t][n])
__global__ __launch_bounds__(64)
void k_prep_S(const float* __restrict__ Wa, u16* __restrict__ BfragS)
{
    int bi = blockIdx.x;            // 192
    int t = bi >> 3, nt = (bi >> 1) & 3, ks = bi & 1;
    int l = threadIdx.x;
    int n = nt * 16 + (l & 15);
    u16 outv[8];
    #pragma unroll
    for (int j = 0; j < 8; ++j) {
        int i = ks * 32 + ((l >> 4) * 8) + j;
        outv[j] = f2b(Wa[(size_t)i * (T_STEPS * N_DIM) + t * N_DIM + n]);
    }
    *reinterpret_cast<int4*>(BfragS + ((size_t)(bi * 64 + l)) * 8) =
        *reinterpret_cast<const int4*>(outv);
}

// Gates B-frags hi/lo
__global__ __launch_bounds__(64)
void k_prep_G(const float* __restrict__ W, const float* __restrict__ U,
              u16* __restrict__ GH, u16* __restrict__ GL)
{
    int bi = blockIdx.x;            // 192
    int ks = bi >> 5, nt = bi & 31;
    int l = threadIdx.x;
    int col = nt * 16 + (l & 15);
    u16 hv[8], lv[8];
    #pragma unroll
    for (int j = 0; j < 8; ++j) {
        int k = ks * 32 + ((l >> 4) * 8) + j;
        float v = (k < 64) ? W[(size_t)k * G4 + col] : U[(size_t)(k - 64) * G4 + col];
        unsigned int ub = __float_as_uint(v);
        u16 hi = (u16)(ub >> 16);
        hv[j] = hi;
        lv[j] = f2b(v - b2f(hi));
    }
    size_t base = ((size_t)(bi * 64 + l)) * 8;
    *reinterpret_cast<int4*>(GH + base) = *reinterpret_cast<const int4*>(hv);
    *reinterpret_cast<int4*>(GL + base) = *reinterpret_cast<const int4*>(lv);
}

// UaT[t][n][hd] = Ua[hd][t][n]
__global__ __launch_bounds__(256)
void k_prep_U(const float* __restrict__ Ua, float* __restrict__ UaT)
{
    int idx = blockIdx.x * 256 + threadIdx.x;    // 196608
    int hd = idx & 127, n = (idx >> 7) & 63, t = idx >> 13;
    UaT[(size_t)t * 8192 + n * 128 + hd] = Ua[(size_t)hd * (T_STEPS * N_DIM) + t * N_DIM + n];
}

// VaT[t][n] = Va[n][t]
__global__ __launch_bounds__(256)
void k_prep_V(const float* __restrict__ Va, float* __restrict__ VaT)
{
    int idx = blockIdx.x * 256 + threadIdx.x;    // 1536
    int n = idx & 63, t = idx >> 6;
    VaT[t * 64 + n] = Va[n * T_STEPS + t];
}

// ---------------- per-step fused kernel: wave-per-batch, M=16 gates ----------------
// 1024 threads = 16 waves; wave w owns batch b0+w for attention; gates GEMM
// packs M=16 batches (full M-util). LDS ~70 KB; 4 barriers per step.
template<bool PRE>
__global__ __launch_bounds__(1024)
void k_step(const float* __restrict__ H, const u16* __restrict__ Hb,
            const u16* __restrict__ BfragS, const u16* __restrict__ GH,
            const u16* __restrict__ GL, const float* __restrict__ UaT,
            const float* __restrict__ VaT, const float* __restrict__ ba,
            const float* __restrict__ W, const float* __restrict__ bias,
            const float* __restrict__ fc_w, const float* __restrict__ fc_b,
            float* __restrict__ y_ws, float* __restrict__ h_ws,
            float* __restrict__ c_ws, float* __restrict__ out, int t)
{
    __shared__ float cs[BPB][HD];                     // 8 KB
    __shared__ float hsv[BPB][HD];                    // 8 KB
    __shared__ float lg[BPB][S];                      // 6 KB
    __shared__ float xs[BPB][I_DIM];                  // 4 KB
    __shared__ float yv[BPB];
    __shared__ float gates[BPB][G4];                  // 32 KB
    __shared__ __align__(16) u16 AFh[6][BPB][32];     // 6 KB
    __shared__ __align__(16) u16 AFl[6][BPB][32];     // 6 KB

    const int tid = threadIdx.x;
    const int w = tid >> 6, l = tid & 63;             // wave = local batch
    const int b0 = blockIdx.x * BPB, b = b0 + w;

    // ---- stage state (wave w loads batch w's state) ----
    {
        cs[w][l]        = c_ws[(size_t)b * HD + l];
        cs[w][l + 64]   = c_ws[(size_t)b * HD + l + 64];
        hsv[w][l]       = h_ws[(size_t)b * HD + l];
        hsv[w][l + 64]  = h_ws[(size_t)b * HD + l + 64];
    }
    if (tid < BPB) yv[tid] = y_ws[b0 + tid];
    __syncthreads();   // B_a

    // ---- score B-frags (precomputed lane layout; shared across batches) ----
    bf16x8 bfr[4][2];
    {
        const bf16x8* bsp = reinterpret_cast<const bf16x8*>(BfragS) + (size_t)t * 8 * 64 + l;
        #pragma unroll
        for (int nt = 0; nt < 4; ++nt)
            #pragma unroll
            for (int ks = 0; ks < 2; ++ks)
                bfr[nt][ks] = bsp[(nt * 2 + ks) * 64];
    }

    // ---- cu[n]: lane n sums all 128 hd (wave-local, no barrier) ----
    float cbn;
    {
        const float4* u4 = reinterpret_cast<const float4*>(UaT + (size_t)t * 8192 + l * 128);
        float p = 0.0f;
        #pragma unroll
        for (int k = 0; k < 32; ++k) {
            float4 uv = u4[k];
            float4 cv = *reinterpret_cast<const float4*>(&cs[w][4 * k]);
            p += uv.x * cv.x + uv.y * cv.y + uv.z * cv.z + uv.w * cv.w;
        }
        cbn = p + ba[t * 64 + l];
    }
    float van = VaT[t * 64 + l];
    float cbv[4], vav[4];
    #pragma unroll
    for (int nt = 0; nt < 4; ++nt) {
        int n = nt * 16 + (l & 15);
        cbv[nt] = __shfl(cbn, n, 64);
        vav[nt] = __shfl(van, n, 64);
    }

    // ---- score GEMM + tanh + reduce: wave does all 6 M-tiles of its batch ----
    const float scale = 0.08838834764831845f; // 1/sqrt(128)
    const u16* hbase = Hb + (size_t)b * (S * I_DIM);
    const float* hbasef = H + (size_t)b * (S * I_DIM);
    const int kp = (l >> 4) * 8;
    for (int mt = 0; mt < 6; ++mt) {
        int row = mt * 16 + (l & 15);
        bf16x8 a0, a1;
        if (PRE) {
            a0 = *reinterpret_cast<const bf16x8*>(hbase + row * I_DIM + kp);
            a1 = *reinterpret_cast<const bf16x8*>(hbase + row * I_DIM + 32 + kp);
        } else {
            const float* hr = hbasef + row * I_DIM;
            u16 t0[8], t1[8];
            #pragma unroll
            for (int j = 0; j < 8; ++j) {
                t0[j] = f2b(hr[kp + j]);
                t1[j] = f2b(hr[32 + kp + j]);
            }
            a0 = *reinterpret_cast<const bf16x8*>(t0);
            a1 = *reinterpret_cast<const bf16x8*>(t1);
        }
        float lgp[4] = {0.f, 0.f, 0.f, 0.f};
        #pragma unroll
        for (int nt = 0; nt < 4; ++nt) {
            f32x4 c = {0.f, 0.f, 0.f, 0.f};
            c = __builtin_amdgcn_mfma_f32_16x16x32_bf16(a0, bfr[nt][0], c, 0, 0, 0);
            c = __builtin_amdgcn_mfma_f32_16x16x32_bf16(a1, bfr[nt][1], c, 0, 0, 0);
            #pragma unroll
            for (int i = 0; i < 4; ++i) {
                float sc = c[i] + cbv[nt];
                sc = fminf(fmaxf(sc, -15.f), 15.f);
                float e = __expf(2.0f * sc);
                float th = 1.0f - 2.0f * frcp(e + 1.0f);
                lgp[i] += th * vav[nt];
            }
        }
        #pragma unroll
        for (int off = 1; off < 16; off <<= 1)
            #pragma unroll
            for (int i = 0; i < 4; ++i) lgp[i] += __shfl_xor(lgp[i], off, 64);
        if ((l & 15) == 0) {
            int g = l >> 4;
            #pragma unroll
            for (int i = 0; i < 4; ++i)
                lg[w][mt * 16 + g * 4 + i] = lgp[i] * scale;
        }
    }

    // ---- softmax over S=96 (wave-local; same wave wrote lg[w]) ----
    {
        float v0 = lg[w][l];
        float v1 = (l < 32) ? lg[w][64 + l] : -1e30f;
        float m = fmaxf(v0, v1);
        #pragma unroll
        for (int off = 32; off; off >>= 1) m = fmaxf(m, __shfl_xor(m, off, 64));
        float e0 = __expf(v0 - m);
        float e1 = (l < 32) ? __expf(v1 - m) : 0.0f;
        float ss = e0 + e1;
        #pragma unroll
        for (int off = 32; off; off >>= 1) ss += __shfl_xor(ss, off, 64);
        float inv = frcp(ss);
        lg[w][l] = e0 * inv;
        if (l < 32) lg[w][64 + l] = e1 * inv;
    }

    // ---- ctx (vectorized): lane handles i-block (l&7)*8, s = (l>>3)+8k ----
    {
        float ctxp[8] = {0.f, 0.f, 0.f, 0.f, 0.f, 0.f, 0.f, 0.f};
        #pragma unroll
        for (int k = 0; k < 12; ++k) {
            int chunk = l + 64 * k;          // bf16x8 chunk index 0..767
            int s = chunk >> 3;
            float beta = lg[w][s];
            if (PRE) {
                int4 v = reinterpret_cast<const int4*>(hbase)[chunk];
                const u16* pv = reinterpret_cast<const u16*>(&v);
                #pragma unroll
                for (int j = 0; j < 8; ++j) ctxp[j] += beta * b2f(pv[j]);
            } else {
                const float4* pf = reinterpret_cast<const float4*>(hbasef) + chunk * 2;
                float4 v0 = pf[0], v1 = pf[1];
                ctxp[0] += beta * v0.x; ctxp[1] += beta * v0.y;
                ctxp[2] += beta * v0.z; ctxp[3] += beta * v0.w;
                ctxp[4] += beta * v1.x; ctxp[5] += beta * v1.y;
                ctxp[6] += beta * v1.z; ctxp[7] += beta * v1.w;
            }
        }
        #pragma unroll
        for (int off = 8; off <= 32; off <<= 1)
            #pragma unroll
            for (int j = 0; j < 8; ++j) ctxp[j] += __shfl_xor(ctxp[j], off, 64);
        if (l < 8) {
            #pragma unroll
            for (int j = 0; j < 8; ++j) xs[w][l * 8 + j] = ctxp[j];
        }
    }
    __syncthreads();   // B_b (xs of all batches ready)

    // ---- build gates A-frags (hi/lo split), 16 batches x 192 K ----
    #pragma unroll
    for (int it = 0; it < 3; ++it) {
        int idx = tid + 1024 * it;   // 0..3071
        int ks = idx >> 9, rem = idx & 511;
        int r = rem >> 5, kk = rem & 31;
        int k = ks * 32 + kk;
        float f = (k < 64) ? xs[r][k] : hsv[r][k - 64];
        unsigned int ub = __float_as_uint(f);
        u16 hi = (u16)(ub >> 16);
        AFh[ks][r][kk] = hi;
        AFl[ks][r][kk] = f2b(f - b2f(hi));
    }
    __syncthreads();   // B_c

    // ---- gates GEMM via MFMA (3-pass split, M=16); wave owns 2 N-tiles ----
    {
        f32x4 acc[2] = {{0.f,0.f,0.f,0.f},{0.f,0.f,0.f,0.f}};
        const int nt0 = w * 2;
        const int r = l & 15;
        #pragma unroll
        for (int ks = 0; ks < 6; ++ks) {
            bf16x8 ah = *reinterpret_cast<const bf16x8*>(&AFh[ks][r][kp]);
            bf16x8 al = *reinterpret_cast<const bf16x8*>(&AFl[ks][r][kp]);
            #pragma unroll
            for (int c2 = 0; c2 < 2; ++c2) {
                size_t base = ((size_t)(ks * 32 + nt0 + c2) * 64 + l);
                bf16x8 bh = reinterpret_cast<const bf16x8*>(GH)[base];
                bf16x8 bl = reinterpret_cast<const bf16x8*>(GL)[base];
                acc[c2] = __builtin_amdgcn_mfma_f32_16x16x32_bf16(ah, bh, acc[c2], 0, 0, 0);
                acc[c2] = __builtin_amdgcn_mfma_f32_16x16x32_bf16(ah, bl, acc[c2], 0, 0, 0);
                acc[c2] = __builtin_amdgcn_mfma_f32_16x16x32_bf16(al, bh, acc[c2], 0, 0, 0);
            }
        }
        // C/D: col = lane&15, row = (lane>>4)*4 + i; rows 0-15 = batches 0-15
        {
            int i0 = (l >> 4) * 4;
            #pragma unroll
            for (int c2 = 0; c2 < 2; ++c2) {
                int j = (nt0 + c2) * 16 + (l & 15);
                float bj = bias[j];
                float wy = W[(size_t)I_DIM * G4 + j];
                #pragma unroll
                for (int i = 0; i < 4; ++i)
                    gates[i0 + i][j] = acc[c2][i] + bj + yv[i0 + i] * wy;
            }
        }
    }
    __syncthreads();   // B_d

    // ---- pointwise LSTM + y: wave w owns batch b (hd = l, l+64) ----
    {
        float yp = 0.0f;
        #pragma unroll
        for (int m = 0; m < 2; ++m) {
            int hd = l + 64 * m;
            float ig = gates[w][hd];
            float fg = gates[w][HD + hd];
            float gg = gates[w][2 * HD + hd];
            float og = gates[w][3 * HD + hd];
            float cold = cs[w][hd];
            float cnew = sigm_f(fg) * cold + sigm_f(ig) * tanh_f(gg);
            float hnew = sigm_f(og) * tanh_f(cnew);
            c_ws[(size_t)b * HD + hd] = cnew;
            h_ws[(size_t)b * HD + hd] = hnew;
            out[(size_t)(B * T_STEPS) + ((size_t)b * T_STEPS + t) * HD + hd] = hnew;
            yp += hnew * fc_w[t * HD + hd];
        }
        #pragma unroll
        for (int off = 32; off; off >>= 1) yp += __shfl_xor(yp, off, 64);
        if (l == 0) {
            float y = yp + fc_b[t];
            y_ws[b] = y;
            out[(size_t)b * T_STEPS + t] = y;
        }
    }
}

extern "C" void kernel_launch(void* const* d_in, const int* in_sizes, int n_in,
                              void* d_out, int out_size, void* d_ws, size_t ws_size,
                              hipStream_t stream)
{
    const float* H    = (const float*)d_in[0];
    const float* y0   = (const float*)d_in[1];
    const float* h0   = (const float*)d_in[2];
    const float* c0   = (const float*)d_in[3];
    const float* Wa   = (const float*)d_in[4];
    const float* Ua   = (const float*)d_in[5];
    const float* ba   = (const float*)d_in[6];
    const float* Va   = (const float*)d_in[7];
    const float* W    = (const float*)d_in[8];
    const float* U    = (const float*)d_in[9];
    const float* bias = (const float*)d_in[10];
    const float* fc_w = (const float*)d_in[11];
    const float* fc_b = (const float*)d_in[12];
    float* out = (float*)d_out;

    u16* BfragS = (u16*)d_ws;                       // 98304 u16
    u16* GH     = BfragS + 98304;                   // 98304
    u16* GL     = GH + 98304;                       // 98304
    float* UaT  = (float*)(GL + 98304);             // 196608 f32
    float* VaT  = UaT + 196608;                     // 1536
    float* h_ws = VaT + 1536;                       // B*HD
    float* c_ws = h_ws + (size_t)B * HD;            // B*HD
    float* y_ws = c_ws + (size_t)B * HD;            // B
    u16*   Hb   = (u16*)(y_ws + B);                 // B*S*I

    size_t need = (size_t)((char*)(Hb + (size_t)B * S * I_DIM) - (char*)d_ws);
    bool pre = ws_size >= need;

    k_init<<<dim3((B * HD + 255) / 256), dim3(256), 0, stream>>>(h0, c0, y0, h_ws, c_ws, y_ws);
    k_prep_S<<<dim3(192), dim3(64), 0, stream>>>(Wa, BfragS);
    k_prep_G<<<dim3(192), dim3(64), 0, stream>>>(W, U, GH, GL);
    k_prep_U<<<dim3(768), dim3(256), 0, stream>>>(Ua, UaT);
    k_prep_V<<<dim3(6), dim3(256), 0, stream>>>(Va, VaT);
    if (pre)
        k_prep<<<dim3(B * S * I_DIM / 8 / 256), dim3(256), 0, stream>>>(H, Hb);

    for (int t = 0; t < T_STEPS; ++t) {
        if (pre)
            k_step<true><<<dim3(B / BPB), dim3(1024), 0, stream>>>(H, Hb, BfragS, GH, GL,
                UaT, VaT, ba, W, bias, fc_w, fc_b, y_ws, h_ws, c_ws, out, t);
        else
            k_step<false><<<dim3(B / BPB), dim3(1024), 0, stream>>>(H, Hb, BfragS, GH, GL,
                UaT, VaT, ba, W, bias, fc_w, fc_b, y_ws, h_ws, c_ws, out, t);
    }
}

// Round 18
// 606.331 us; speedup vs baseline: 3.0101x; 1.4532x over previous
//
#include <hip/hip_runtime.h>
#include <hip/hip_bf16.h>

#define B 4096
#define S 96
#define I_DIM 64
#define HD 128
#define T_STEPS 24
#define N_DIM 64
#define G4 512   // 4*HD
#define BPB 16   // batches per block: one wave each (16 waves, 1024 threads)

typedef unsigned short u16;
typedef __attribute__((ext_vector_type(8))) short bf16x8;
typedef __attribute__((ext_vector_type(4))) float f32x4;

__device__ __forceinline__ u16 f2b(float f) {
    unsigned int u = __float_as_uint(f);
    unsigned int r = (u + 0x7FFFu + ((u >> 16) & 1u)) >> 16;
    return (u16)r;
}
__device__ __forceinline__ float b2f(u16 x) {
    return __uint_as_float(((unsigned int)x) << 16);
}
__device__ __forceinline__ float frcp(float x) { return __builtin_amdgcn_rcpf(x); }
__device__ __forceinline__ float sigm_f(float x) { return frcp(1.0f + __expf(-x)); }
__device__ __forceinline__ float tanh_f(float x) {
    x = fminf(fmaxf(x, -15.f), 15.f);
    float e = __expf(2.0f * x);
    return 1.0f - 2.0f * frcp(e + 1.0f);
}

// ---------------- one-time prep kernels ----------------

__global__ __launch_bounds__(256)
void k_init(const float* __restrict__ h0, const float* __restrict__ c0,
            const float* __restrict__ y0,
            float* __restrict__ h_ws, float* __restrict__ c_ws,
            float* __restrict__ y_ws)
{
    int idx = blockIdx.x * 256 + threadIdx.x;
    if (idx < B * HD) {
        h_ws[idx] = h0[idx];
        c_ws[idx] = c0[idx];
    }
    if (idx < B) y_ws[idx] = y0[idx];
}

// H f32 -> bf16 linear
__global__ __launch_bounds__(256)
void k_prep(const float* __restrict__ H, u16* __restrict__ Hb)
{
    size_t idx = (size_t)blockIdx.x * 256 + threadIdx.x;
    const float4* src = reinterpret_cast<const float4*>(H) + idx * 2;
    float4 v0 = src[0], v1 = src[1];
    ushort4 p0 = { f2b(v0.x), f2b(v0.y), f2b(v0.z), f2b(v0.w) };
    ushort4 p1 = { f2b(v1.x), f2b(v1.y), f2b(v1.z), f2b(v1.w) };
    ushort4* dst = reinterpret_cast<ushort4*>(Hb + idx * 8);
    dst[0] = p0;
    dst[1] = p1;
}

// Score B-frags: group bi = t*8 + nt*2 + ks; elem ((bi*64)+l)*8+j = bf16(Wa[i][t][n])
__global__ __launch_bounds__(64)
void k_prep_S(const float* __restrict__ Wa, u16* __restrict__ BfragS)
{
    int bi = blockIdx.x;            // 192
    int t = bi >> 3, nt = (bi >> 1) & 3, ks = bi & 1;
    int l = threadIdx.x;
    int n = nt * 16 + (l & 15);
    u16 outv[8];
    #pragma unroll
    for (int j = 0; j < 8; ++j) {
        int i = ks * 32 + ((l >> 4) * 8) + j;
        outv[j] = f2b(Wa[(size_t)i * (T_STEPS * N_DIM) + t * N_DIM + n]);
    }
    *reinterpret_cast<int4*>(BfragS + ((size_t)(bi * 64 + l)) * 8) =
        *reinterpret_cast<const int4*>(outv);
}

// Gates B-frags hi/lo
__global__ __launch_bounds__(64)
void k_prep_G(const float* __restrict__ W, const float* __restrict__ U,
              u16* __restrict__ GH, u16* __restrict__ GL)
{
    int bi = blockIdx.x;            // 192
    int ks = bi >> 5, nt = bi & 31;
    int l = threadIdx.x;
    int col = nt * 16 + (l & 15);
    u16 hv[8], lv[8];
    #pragma unroll
    for (int j = 0; j < 8; ++j) {
        int k = ks * 32 + ((l >> 4) * 8) + j;
        float v = (k < 64) ? W[(size_t)k * G4 + col] : U[(size_t)(k - 64) * G4 + col];
        unsigned int ub = __float_as_uint(v);
        u16 hi = (u16)(ub >> 16);
        hv[j] = hi;
        lv[j] = f2b(v - b2f(hi));
    }
    size_t base = ((size_t)(bi * 64 + l)) * 8;
    *reinterpret_cast<int4*>(GH + base) = *reinterpret_cast<const int4*>(hv);
    *reinterpret_cast<int4*>(GL + base) = *reinterpret_cast<const int4*>(lv);
}

// UaT[t][n][hd] = Ua[hd][t][n]
__global__ __launch_bounds__(256)
void k_prep_U(const float* __restrict__ Ua, float* __restrict__ UaT)
{
    int idx = blockIdx.x * 256 + threadIdx.x;    // 196608
    int hd = idx & 127, n = (idx >> 7) & 63, t = idx >> 13;
    UaT[(size_t)t * 8192 + n * 128 + hd] = Ua[(size_t)hd * (T_STEPS * N_DIM) + t * N_DIM + n];
}

// VaT[t][n] = Va[n][t]
__global__ __launch_bounds__(256)
void k_prep_V(const float* __restrict__ Va, float* __restrict__ VaT)
{
    int idx = blockIdx.x * 256 + threadIdx.x;    // 1536
    int n = idx & 63, t = idx >> 6;
    VaT[t * 64 + n] = Va[n * T_STEPS + t];
}

// ---------------- per-step fused kernel: wave-per-batch, M=16 gates ----------------
// 1024 threads = 16 waves; wave w owns batch b0+w for attention; gates GEMM
// packs M=16 batches. UaT[t] staged to LDS (pad-129 rows -> 2-way-free banks).
template<bool PRE>
__global__ __launch_bounds__(1024)
void k_step(const float* __restrict__ H, const u16* __restrict__ Hb,
            const u16* __restrict__ BfragS, const u16* __restrict__ GH,
            const u16* __restrict__ GL, const float* __restrict__ UaT,
            const float* __restrict__ VaT, const float* __restrict__ ba,
            const float* __restrict__ W, const float* __restrict__ bias,
            const float* __restrict__ fc_w, const float* __restrict__ fc_b,
            float* __restrict__ y_ws, float* __restrict__ h_ws,
            float* __restrict__ c_ws, float* __restrict__ out, int t)
{
    __shared__ float cs[BPB][HD];                     // 8 KB
    __shared__ float hsv[BPB][HD];                    // 8 KB
    __shared__ float lg[BPB][S];                      // 6 KB
    __shared__ float xs[BPB][I_DIM];                  // 4 KB
    __shared__ float yv[BPB];
    __shared__ float gates[BPB][G4];                  // 32 KB
    __shared__ __align__(16) u16 AFh[6][BPB][32];     // 6 KB
    __shared__ __align__(16) u16 AFl[6][BPB][32];     // 6 KB
    __shared__ float UaL[N_DIM][HD + 1];              // 33 KB, pad-129

    const int tid = threadIdx.x;
    const int w = tid >> 6, l = tid & 63;             // wave = local batch
    const int b0 = blockIdx.x * BPB, b = b0 + w;

    // ---- stage UaT[t] (32 KB, coalesced read) into padded LDS ----
    {
        const float4* src = reinterpret_cast<const float4*>(UaT + (size_t)t * 8192);
        #pragma unroll
        for (int k = 0; k < 2; ++k) {
            int e4 = tid + 1024 * k;        // float4 idx 0..2047
            float4 v = src[e4];
            int e = e4 * 4;
            int n = e >> 7, hd = e & 127;
            UaL[n][hd]     = v.x;
            UaL[n][hd + 1] = v.y;
            UaL[n][hd + 2] = v.z;
            UaL[n][hd + 3] = v.w;
        }
    }
    // ---- stage state (wave w loads batch w's state) ----
    {
        cs[w][l]        = c_ws[(size_t)b * HD + l];
        cs[w][l + 64]   = c_ws[(size_t)b * HD + l + 64];
        hsv[w][l]       = h_ws[(size_t)b * HD + l];
        hsv[w][l + 64]  = h_ws[(size_t)b * HD + l + 64];
    }
    if (tid < BPB) yv[tid] = y_ws[b0 + tid];
    __syncthreads();   // B_a

    // ---- score B-frags (precomputed lane layout; shared across batches) ----
    bf16x8 bfr[4][2];
    {
        const bf16x8* bsp = reinterpret_cast<const bf16x8*>(BfragS) + (size_t)t * 8 * 64 + l;
        #pragma unroll
        for (int nt = 0; nt < 4; ++nt)
            #pragma unroll
            for (int ks = 0; ks < 2; ++ks)
                bfr[nt][ks] = bsp[(nt * 2 + ks) * 64];
    }

    // ---- cu[n]: lane n sums all 128 hd from LDS (2-way-free banks) ----
    float cbn;
    {
        float p = 0.0f;
        #pragma unroll 16
        for (int hd = 0; hd < HD; ++hd)
            p += UaL[l][hd] * cs[w][hd];
        cbn = p + ba[t * 64 + l];
    }
    float van = VaT[t * 64 + l];
    float cbv[4], vav[4];
    #pragma unroll
    for (int nt = 0; nt < 4; ++nt) {
        int n = nt * 16 + (l & 15);
        cbv[nt] = __shfl(cbn, n, 64);
        vav[nt] = __shfl(van, n, 64);
    }

    // ---- score GEMM + tanh + reduce: wave does all 6 M-tiles of its batch ----
    const float scale = 0.08838834764831845f; // 1/sqrt(128)
    const u16* hbase = Hb + (size_t)b * (S * I_DIM);
    const float* hbasef = H + (size_t)b * (S * I_DIM);
    const int kp = (l >> 4) * 8;
    for (int mt = 0; mt < 6; ++mt) {
        int row = mt * 16 + (l & 15);
        bf16x8 a0, a1;
        if (PRE) {
            a0 = *reinterpret_cast<const bf16x8*>(hbase + row * I_DIM + kp);
            a1 = *reinterpret_cast<const bf16x8*>(hbase + row * I_DIM + 32 + kp);
        } else {
            const float* hr = hbasef + row * I_DIM;
            u16 t0[8], t1[8];
            #pragma unroll
            for (int j = 0; j < 8; ++j) {
                t0[j] = f2b(hr[kp + j]);
                t1[j] = f2b(hr[32 + kp + j]);
            }
            a0 = *reinterpret_cast<const bf16x8*>(t0);
            a1 = *reinterpret_cast<const bf16x8*>(t1);
        }
        float lgp[4] = {0.f, 0.f, 0.f, 0.f};
        #pragma unroll
        for (int nt = 0; nt < 4; ++nt) {
            f32x4 c = {0.f, 0.f, 0.f, 0.f};
            c = __builtin_amdgcn_mfma_f32_16x16x32_bf16(a0, bfr[nt][0], c, 0, 0, 0);
            c = __builtin_amdgcn_mfma_f32_16x16x32_bf16(a1, bfr[nt][1], c, 0, 0, 0);
            #pragma unroll
            for (int i = 0; i < 4; ++i) {
                float sc = c[i] + cbv[nt];
                sc = fminf(fmaxf(sc, -15.f), 15.f);
                float e = __expf(2.0f * sc);
                float th = 1.0f - 2.0f * frcp(e + 1.0f);
                lgp[i] += th * vav[nt];
            }
        }
        #pragma unroll
        for (int off = 1; off < 16; off <<= 1)
            #pragma unroll
            for (int i = 0; i < 4; ++i) lgp[i] += __shfl_xor(lgp[i], off, 64);
        if ((l & 15) == 0) {
            int g = l >> 4;
            #pragma unroll
            for (int i = 0; i < 4; ++i)
                lg[w][mt * 16 + g * 4 + i] = lgp[i] * scale;
        }
    }

    // ---- softmax over S=96 (wave-local; same wave wrote lg[w]) ----
    {
        float v0 = lg[w][l];
        float v1 = (l < 32) ? lg[w][64 + l] : -1e30f;
        float m = fmaxf(v0, v1);
        #pragma unroll
        for (int off = 32; off; off >>= 1) m = fmaxf(m, __shfl_xor(m, off, 64));
        float e0 = __expf(v0 - m);
        float e1 = (l < 32) ? __expf(v1 - m) : 0.0f;
        float ss = e0 + e1;
        #pragma unroll
        for (int off = 32; off; off >>= 1) ss += __shfl_xor(ss, off, 64);
        float inv = frcp(ss);
        lg[w][l] = e0 * inv;
        if (l < 32) lg[w][64 + l] = e1 * inv;
    }

    // ---- ctx (vectorized): lane handles bf16x8 chunks, reduce over s ----
    {
        float ctxp[8] = {0.f, 0.f, 0.f, 0.f, 0.f, 0.f, 0.f, 0.f};
        #pragma unroll
        for (int k = 0; k < 12; ++k) {
            int chunk = l + 64 * k;          // bf16x8 chunk index 0..767
            int s = chunk >> 3;
            float beta = lg[w][s];
            if (PRE) {
                int4 v = reinterpret_cast<const int4*>(hbase)[chunk];
                const u16* pv = reinterpret_cast<const u16*>(&v);
                #pragma unroll
                for (int j = 0; j < 8; ++j) ctxp[j] += beta * b2f(pv[j]);
            } else {
                const float4* pf = reinterpret_cast<const float4*>(hbasef) + chunk * 2;
                float4 v0 = pf[0], v1 = pf[1];
                ctxp[0] += beta * v0.x; ctxp[1] += beta * v0.y;
                ctxp[2] += beta * v0.z; ctxp[3] += beta * v0.w;
                ctxp[4] += beta * v1.x; ctxp[5] += beta * v1.y;
                ctxp[6] += beta * v1.z; ctxp[7] += beta * v1.w;
            }
        }
        #pragma unroll
        for (int off = 8; off <= 32; off <<= 1)
            #pragma unroll
            for (int j = 0; j < 8; ++j) ctxp[j] += __shfl_xor(ctxp[j], off, 64);
        if (l < 8) {
            #pragma unroll
            for (int j = 0; j < 8; ++j) xs[w][l * 8 + j] = ctxp[j];
        }
    }
    __syncthreads();   // B_b (xs of all batches ready)

    // ---- build gates A-frags (hi/lo split), 16 batches x 192 K ----
    #pragma unroll
    for (int it = 0; it < 3; ++it) {
        int idx = tid + 1024 * it;   // 0..3071
        int ks = idx >> 9, rem = idx & 511;
        int r = rem >> 5, kk = rem & 31;
        int k = ks * 32 + kk;
        float f = (k < 64) ? xs[r][k] : hsv[r][k - 64];
        unsigned int ub = __float_as_uint(f);
        u16 hi = (u16)(ub >> 16);
        AFh[ks][r][kk] = hi;
        AFl[ks][r][kk] = f2b(f - b2f(hi));
    }
    __syncthreads();   // B_c

    // ---- gates GEMM via MFMA (3-pass split, M=16); wave owns 2 N-tiles ----
    {
        f32x4 acc[2] = {{0.f,0.f,0.f,0.f},{0.f,0.f,0.f,0.f}};
        const int nt0 = w * 2;
        const int r = l & 15;
        #pragma unroll
        for (int ks = 0; ks < 6; ++ks) {
            bf16x8 ah = *reinterpret_cast<const bf16x8*>(&AFh[ks][r][kp]);
            bf16x8 al = *reinterpret_cast<const bf16x8*>(&AFl[ks][r][kp]);
            #pragma unroll
            for (int c2 = 0; c2 < 2; ++c2) {
                size_t base = ((size_t)(ks * 32 + nt0 + c2) * 64 + l);
                bf16x8 bh = reinterpret_cast<const bf16x8*>(GH)[base];
                bf16x8 bl = reinterpret_cast<const bf16x8*>(GL)[base];
                acc[c2] = __builtin_amdgcn_mfma_f32_16x16x32_bf16(ah, bh, acc[c2], 0, 0, 0);
                acc[c2] = __builtin_amdgcn_mfma_f32_16x16x32_bf16(ah, bl, acc[c2], 0, 0, 0);
                acc[c2] = __builtin_amdgcn_mfma_f32_16x16x32_bf16(al, bh, acc[c2], 0, 0, 0);
            }
        }
        // C/D: col = lane&15, row = (lane>>4)*4 + i; rows 0-15 = batches 0-15
        {
            int i0 = (l >> 4) * 4;
            #pragma unroll
            for (int c2 = 0; c2 < 2; ++c2) {
                int j = (nt0 + c2) * 16 + (l & 15);
                float bj = bias[j];
                float wy = W[(size_t)I_DIM * G4 + j];
                #pragma unroll
                for (int i = 0; i < 4; ++i)
                    gates[i0 + i][j] = acc[c2][i] + bj + yv[i0 + i] * wy;
            }
        }
    }
    __syncthreads();   // B_d

    // ---- pointwise LSTM + y: wave w owns batch b (hd = l, l+64) ----
    {
        float yp = 0.0f;
        #pragma unroll
        for (int m = 0; m < 2; ++m) {
            int hd = l + 64 * m;
            float ig = gates[w][hd];
            float fg = gates[w][HD + hd];
            float gg = gates[w][2 * HD + hd];
            float og = gates[w][3 * HD + hd];
            float cold = cs[w][hd];
            float cnew = sigm_f(fg) * cold + sigm_f(ig) * tanh_f(gg);
            float hnew = sigm_f(og) * tanh_f(cnew);
            c_ws[(size_t)b * HD + hd] = cnew;
            h_ws[(size_t)b * HD + hd] = hnew;
            out[(size_t)(B * T_STEPS) + ((size_t)b * T_STEPS + t) * HD + hd] = hnew;
            yp += hnew * fc_w[t * HD + hd];
        }
        #pragma unroll
        for (int off = 32; off; off >>= 1) yp += __shfl_xor(yp, off, 64);
        if (l == 0) {
            float y = yp + fc_b[t];
            y_ws[b] = y;
            out[(size_t)b * T_STEPS + t] = y;
        }
    }
}

extern "C" void kernel_launch(void* const* d_in, const int* in_sizes, int n_in,
                              void* d_out, int out_size, void* d_ws, size_t ws_size,
                              hipStream_t stream)
{
    const float* H    = (const float*)d_in[0];
    const float* y0   = (const float*)d_in[1];
    const float* h0   = (const float*)d_in[2];
    const float* c0   = (const float*)d_in[3];
    const float* Wa   = (const float*)d_in[4];
    const float* Ua   = (const float*)d_in[5];
    const float* ba   = (const float*)d_in[6];
    const float* Va   = (const float*)d_in[7];
    const float* W    = (const float*)d_in[8];
    const float* U    = (const float*)d_in[9];
    const float* bias = (const float*)d_in[10];
    const float* fc_w = (const float*)d_in[11];
    const float* fc_b = (const float*)d_in[12];
    float* out = (float*)d_out;

    u16* BfragS = (u16*)d_ws;                       // 98304 u16
    u16* GH     = BfragS + 98304;                   // 98304
    u16* GL     = GH + 98304;                       // 98304
    float* UaT  = (float*)(GL + 98304);             // 196608 f32
    float* VaT  = UaT + 196608;                     // 1536
    float* h_ws = VaT + 1536;                       // B*HD
    float* c_ws = h_ws + (size_t)B * HD;            // B*HD
    float* y_ws = c_ws + (size_t)B * HD;            // B
    u16*   Hb   = (u16*)(y_ws + B);                 // B*S*I

    size_t need = (size_t)((char*)(Hb + (size_t)B * S * I_DIM) - (char*)d_ws);
    bool pre = ws_size >= need;

    k_init<<<dim3((B * HD + 255) / 256), dim3(256), 0, stream>>>(h0, c0, y0, h_ws, c_ws, y_ws);
    k_prep_S<<<dim3(192), dim3(64), 0, stream>>>(Wa, BfragS);
    k_prep_G<<<dim3(192), dim3(64), 0, stream>>>(W, U, GH, GL);
    k_prep_U<<<dim3(768), dim3(256), 0, stream>>>(Ua, UaT);
    k_prep_V<<<dim3(6), dim3(256), 0, stream>>>(Va, VaT);
    if (pre)
        k_prep<<<dim3(B * S * I_DIM / 8 / 256), dim3(256), 0, stream>>>(H, Hb);

    for (int t = 0; t < T_STEPS; ++t) {
        if (pre)
            k_step<true><<<dim3(B / BPB), dim3(1024), 0, stream>>>(H, Hb, BfragS, GH, GL,
                UaT, VaT, ba, W, bias, fc_w, fc_b, y_ws, h_ws, c_ws, out, t);
        else
            k_step<false><<<dim3(B / BPB), dim3(1024), 0, stream>>>(H, Hb, BfragS, GH, GL,
                UaT, VaT, ba, W, bias, fc_w, fc_b, y_ws, h_ws, c_ws, out, t);
    }
}